// Round 1
// 169.133 us; speedup vs baseline: 1.0038x; 1.0038x over previous
//
#include <hip/hip_runtime.h>
#include <math.h>

using bf16x8 = __attribute__((ext_vector_type(8))) __bf16;
using f32x4  = __attribute__((ext_vector_type(4))) float;

#if __has_builtin(__builtin_amdgcn_exp2f)
#define EXP2F(x) __builtin_amdgcn_exp2f(x)
#else
#define EXP2F(x) exp2f(x)
#endif

__device__ __forceinline__ unsigned short f2bf(float f) {
  unsigned u = __float_as_uint(f);
  unsigned r = u + 0x7fffu + ((u >> 16) & 1u);
  return (unsigned short)(r >> 16);
}

// HW packed f32->bf16 (RNE, same rounding as f2bf). No builtin on gfx950 -> asm.
__device__ __forceinline__ unsigned cvt_pk_bf16(float a, float b) {
  unsigned r;
  asm("v_cvt_pk_bf16_f32 %0, %1, %2" : "=v"(r) : "v"(a), "v"(b));
  return r;
}
__device__ __forceinline__ uint2 pk4(float a, float b, float c, float d) {
  uint2 r; r.x = cvt_pk_bf16(a, b); r.y = cvt_pk_bf16(c, d); return r;
}

__device__ __forceinline__ f32x4 mfma16(uint4 a, uint4 b, f32x4 c) {
  return __builtin_amdgcn_mfma_f32_16x16x32_bf16(
      __builtin_bit_cast(bf16x8, a), __builtin_bit_cast(bf16x8, b), c, 0, 0, 0);
}
__device__ __forceinline__ float swz_xor16(float v) {
  return __int_as_float(__builtin_amdgcn_ds_swizzle(__float_as_int(v), 0x401F));
}

// B-fragment swizzled layout for mfma_f32_16x16x32_bf16:
// element (k, n) -> chunk index (((n>>4)*2 + (k>>5))*64 + ((k>>3)&3)*16 + (n&15))*8 + (k&7)
#define FRAG_OFF(k, n) (((((n) >> 4) * 2 + ((k) >> 5)) * 64 + (((k) >> 3) & 3) * 16 + ((n) & 15)) * 8 + ((k) & 7))

// attention score prescale: (1/sqrt(8)) * log2(e) folded into AQ/qb2
#define ATT_C 0.51006997f

// ---------------- precompute: bf16 weights + algebraic folds -> d_ws ----------------
// wsb (ushort): W1[3][4096]@0  W2[3][4096]@12288  PM1A@24576  PM2@28672
//               AQ@32768  AK@36864  AV@40960  MO@45056  OUT@49152
// wsf (float):  Cpat[4096]@0  geoT[4096]@4096  qb2@8192 kb2@8256 vb2@8320
__global__ void precompute_kernel(
    const float* __restrict__ conv1_w, const float* __restrict__ conv2_w,
    const float* __restrict__ pm1_w, const float* __restrict__ pm1_b,
    const float* __restrict__ pm2_w,
    const float* __restrict__ q_w, const float* __restrict__ q_b,
    const float* __restrict__ k_w, const float* __restrict__ k_b,
    const float* __restrict__ v_w, const float* __restrict__ v_b,
    const float* __restrict__ in_w, const float* __restrict__ in_b,
    const float* __restrict__ mo_w, const float* __restrict__ out_w,
    const float* __restrict__ pattern, const float* __restrict__ points,
    const int* __restrict__ adjacency,
    unsigned short* __restrict__ wsb, float* __restrict__ wsf) {
  int idx = blockIdx.x * 256 + threadIdx.x;
  if (idx < 12288) {                       // W1_t[oc][c] = conv1_w[oc][c][t]
    int t = idx >> 12, rem = idx & 4095;
    int oc = rem >> 6, c = rem & 63;
    wsb[idx] = f2bf(conv1_w[(oc * 64 + c) * 3 + t]);
  } else if (idx < 24576) {                // W2_t block-diagonal dense
    int i2 = idx - 12288;
    int t = i2 >> 12, rem = i2 & 4095;
    int oc = rem >> 6, ci = rem & 63;
    float v = ((ci >> 4) == (oc >> 4)) ? conv2_w[(oc * 16 + (ci & 15)) * 3 + t] : 0.0f;
    wsb[idx] = f2bf(v);
  } else if (idx < 28672) {                // PM1A = pm1_w[:, :64]
    int rem = idx - 24576;
    wsb[idx] = f2bf(pm1_w[(rem >> 6) * 80 + (rem & 63)]);
  } else if (idx < 32768) {                // PM2
    wsb[idx] = f2bf(pm2_w[idx - 28672]);
  } else if (idx < 36864) {                // AQ = (wq @ q_w) * ATT_C
    int rem = idx - 32768; int c = rem >> 6, k = rem & 63;
    float s = 0.f;
    #pragma unroll 8
    for (int j = 0; j < 64; ++j) s += in_w[c * 64 + j] * q_w[j * 64 + k];
    wsb[idx] = f2bf(s * ATT_C);
  } else if (idx < 40960) {                // AK = wk @ k_w
    int rem = idx - 36864; int c = rem >> 6, k = rem & 63;
    float s = 0.f;
    #pragma unroll 8
    for (int j = 0; j < 64; ++j) s += in_w[(64 + c) * 64 + j] * k_w[j * 64 + k];
    wsb[idx] = f2bf(s);
  } else if (idx < 45056) {                // AV = wv @ v_w
    int rem = idx - 40960; int c = rem >> 6, k = rem & 63;
    float s = 0.f;
    #pragma unroll 8
    for (int j = 0; j < 64; ++j) s += in_w[(128 + c) * 64 + j] * v_w[j * 64 + k];
    wsb[idx] = f2bf(s);
  } else if (idx < 49152) {                // MO
    wsb[idx] = f2bf(mo_w[idx - 45056]);
  } else if (idx < 53248) {                // OUT
    wsb[idx] = f2bf(out_w[idx - 49152]);
  } else if (idx < 57344) {                // Cpat[c][n] = pm1_w[:,64:] @ pat^T + pm1_b
    int rem = idx - 53248; int c = rem >> 6, n = rem & 63;
    float s = pm1_b[c];
    #pragma unroll
    for (int cp = 0; cp < 16; ++cp) s += pm1_w[c * 80 + 64 + cp] * pattern[n * 16 + cp];
    wsf[rem] = s;
  } else if (idx < 61440) {                // geoT[c][n] = geo[n][c]
    int rem = idx - 57344; int c = rem >> 6, n = rem & 63;
    float dd = 1e-12f;
    #pragma unroll
    for (int i = 0; i < 3; ++i) { float d = points[n * 3 + i] - points[c * 3 + i]; dd += d * d; }
    float dist = sqrtf(dd);
    wsf[4096 + rem] = (adjacency[n * 64 + c] > 0) ? 0.5f : (-0.1f / (1.0f + dist));
  } else if (idx < 61632) {                // fused qkv biases (q scaled by ATT_C)
    int rem = idx - 61440; int which = rem >> 6, c = rem & 63;
    if (which == 0) {
      float s = in_b[c];
      for (int j = 0; j < 64; ++j) s += in_w[c * 64 + j] * q_b[j];
      wsf[8192 + c] = s * ATT_C;
    } else if (which == 1) {
      float s = in_b[64 + c];
      for (int j = 0; j < 64; ++j) s += in_w[(64 + c) * 64 + j] * k_b[j];
      wsf[8256 + c] = s;
    } else {
      float s = in_b[128 + c];
      for (int j = 0; j < 64; ++j) s += in_w[(128 + c) * 64 + j] * v_b[j];
      wsf[8320 + c] = s;
    }
  }
}

// per-wave 64x64x64 GEMM: acc[nt] over rows c in [16w, 16w+16)
__device__ __forceinline__ void gemm64(const unsigned short* __restrict__ Wg,
                                       const unsigned short* Bf,
                                       int w, int lane, f32x4 acc[4]) {
  const int l15 = lane & 15, lq = lane >> 4;
  #pragma unroll
  for (int s = 0; s < 2; ++s) {
    bf16x8 a = *reinterpret_cast<const bf16x8*>(Wg + (16 * w + l15) * 64 + s * 32 + lq * 8);
    #pragma unroll
    for (int nt = 0; nt < 4; ++nt) {
      bf16x8 bb = *reinterpret_cast<const bf16x8*>(Bf + ((nt * 2 + s) * 64 + lane) * 8);
      acc[nt] = __builtin_amdgcn_mfma_f32_16x16x32_bf16(a, bb, acc[nt], 0, 0, 0);
    }
  }
}

// LDS pool 35840 B (shorts idx unless noted), phase-overlaid:
//  SLOT_A @0     (8KB):  XF(0-1) PIF(2-3) PFF(4-5) CTXF(6-7) HNF(8-9)
//  SLOT_B @4096  (9216B): Y1F(1-2) T1F(3-4) Q[n][72](5-6)
//  KBASE  @8704  (9216B): K[n][72](5-6)
//  VBASE  @13312 (9216B): zero-guard(ph1-2) V[c][72](5-6a) Pscr(6b) LN scratch(8)
//  H32 f32 idx 2048, stride 65 (7-8): overlays SLOT_B+KBASE (Q,K dead)
#define SLOT_B 4096
#define KBASE  8704
#define VBASE  13312
#define H32F   2048   /* f32 idx */
#define LNS    6656   /* f32 idx */

__global__ __launch_bounds__(256, 4) void fused_kernel(
    const float* __restrict__ x,
    const unsigned short* __restrict__ wsb, const float* __restrict__ wsf,
    const float* __restrict__ conv1_b, const float* __restrict__ conv2_b,
    const float* __restrict__ pm2_b, const float* __restrict__ mo_b,
    const float* __restrict__ out_b, const float* __restrict__ ln_g,
    const float* __restrict__ ln_beta, float* __restrict__ out) {
  __shared__ __align__(16) unsigned char smem_raw[35840];
  unsigned short* S16 = reinterpret_cast<unsigned short*>(smem_raw);
  float* S32 = reinterpret_cast<float*>(smem_raw);

  const int tid = threadIdx.x;
  const int b = blockIdx.x;
  const int lane = tid & 63;
  const int w = tid >> 6;
  const int l15 = lane & 15;
  const int lq = lane >> 4;
  const int c0 = 16 * w + lq * 4;   // D-frag row base for this lane
  f32x4 pfs[4];                     // pf residual, D-layout, ph4 -> ph7

  // ---------- Phase 0: zero-guard + stage x -> XF ----------
  // Wave w owns rows c in [16w, 16w+16), column n = lane. Each global load inst
  // is a coalesced 256B (lanes sweep n). FRAG layout is contiguous in (c&7), so
  // 8 rows pack into one 16B ds_write_b128. 8 cvt_pk + 2 vector stores/thread.
  if (tid < 8) S16[VBASE + tid] = 0;   // 16B zero chunk for OOB shifted reads
  {
    const float* xb = x + b * 4096 + w * 16 * 64 + lane;
    float v[16];
    #pragma unroll
    for (int j = 0; j < 16; ++j) v[j] = xb[j * 64];
    #pragma unroll
    for (int g = 0; g < 2; ++g) {
      uint4 u;
      u.x = cvt_pk_bf16(v[g * 8 + 0], v[g * 8 + 1]);
      u.y = cvt_pk_bf16(v[g * 8 + 2], v[g * 8 + 3]);
      u.z = cvt_pk_bf16(v[g * 8 + 4], v[g * 8 + 5]);
      u.w = cvt_pk_bf16(v[g * 8 + 6], v[g * 8 + 7]);
      *reinterpret_cast<uint4*>(S16 + FRAG_OFF(w * 16 + g * 8, lane)) = u;
    }
  }
  __syncthreads();

  // ---------- conv helper: sum_t W_t @ shift(src, t-1), with zero-guard ----------
  auto conv_pass = [&](const unsigned short* Wg, int srcBase, f32x4 acc[4]) {
    bf16x8 a6[3][2];
    #pragma unroll
    for (int t = 0; t < 3; ++t)
      #pragma unroll
      for (int s = 0; s < 2; ++s)
        a6[t][s] = *reinterpret_cast<const bf16x8*>(Wg + t * 4096 + (16 * w + l15) * 64 + s * 32 + lq * 8);
    #pragma unroll
    for (int nt = 0; nt < 4; ++nt) {
      #pragma unroll
      for (int t = 0; t < 3; ++t) {
        int np = nt * 16 + l15 + (t - 1);
        bool ok = (unsigned)np < 64u;
        int a = srcBase + (((np >> 4) * 2) * 64 + lq * 16 + (np & 15)) * 8;
        int A0 = ok ? a : VBASE;
        int A1 = ok ? (a + 512) : VBASE;
        bf16x8 b0 = *reinterpret_cast<const bf16x8*>(S16 + A0);
        bf16x8 b1 = *reinterpret_cast<const bf16x8*>(S16 + A1);
        acc[nt] = __builtin_amdgcn_mfma_f32_16x16x32_bf16(a6[t][0], b0, acc[nt], 0, 0, 0);
        acc[nt] = __builtin_amdgcn_mfma_f32_16x16x32_bf16(a6[t][1], b1, acc[nt], 0, 0, 0);
      }
    }
  };

  // ---------- Phase 1: conv1 -> Y1F @SLOT_B ----------
  {
    f32x4 acc[4] = {};
    conv_pass(wsb, 0, acc);
    float bia[4] = {conv1_b[c0], conv1_b[c0 + 1], conv1_b[c0 + 2], conv1_b[c0 + 3]};
    #pragma unroll
    for (int nt = 0; nt < 4; ++nt) {
      int n = nt * 16 + l15;
      uint2 u = pk4(fmaxf(acc[nt][0] + bia[0], 0.f), fmaxf(acc[nt][1] + bia[1], 0.f),
                    fmaxf(acc[nt][2] + bia[2], 0.f), fmaxf(acc[nt][3] + bia[3], 0.f));
      *reinterpret_cast<uint2*>(S16 + SLOT_B + FRAG_OFF(c0, n)) = u;
    }
  }
  __syncthreads();

  // ---------- Phase 2: conv2 -> PIF @SLOT_A ----------
  {
    f32x4 acc[4] = {};
    conv_pass(wsb + 12288, SLOT_B, acc);
    float bia[4] = {conv2_b[c0], conv2_b[c0 + 1], conv2_b[c0 + 2], conv2_b[c0 + 3]};
    #pragma unroll
    for (int nt = 0; nt < 4; ++nt) {
      int n = nt * 16 + l15;
      uint2 u = pk4(fmaxf(acc[nt][0] + bia[0], 0.f), fmaxf(acc[nt][1] + bia[1], 0.f),
                    fmaxf(acc[nt][2] + bia[2], 0.f), fmaxf(acc[nt][3] + bia[3], 0.f));
      *reinterpret_cast<uint2*>(S16 + FRAG_OFF(c0, n)) = u;
    }
  }
  __syncthreads();

  // ---------- Phase 3: pm1: relu(PM1A @ PIF + Cpat) -> T1F @SLOT_B ----------
  {
    f32x4 acc[4] = {};
    gemm64(wsb + 24576, S16, w, lane, acc);
    #pragma unroll
    for (int nt = 0; nt < 4; ++nt) {
      int n = nt * 16 + l15;
      uint2 u = pk4(fmaxf(acc[nt][0] + wsf[(c0 + 0) * 64 + n], 0.f),
                    fmaxf(acc[nt][1] + wsf[(c0 + 1) * 64 + n], 0.f),
                    fmaxf(acc[nt][2] + wsf[(c0 + 2) * 64 + n], 0.f),
                    fmaxf(acc[nt][3] + wsf[(c0 + 3) * 64 + n], 0.f));
      *reinterpret_cast<uint2*>(S16 + SLOT_B + FRAG_OFF(c0, n)) = u;
    }
  }
  __syncthreads();

  // ---------- Phase 4: pm2: PM2 @ T1F + b -> PFF @SLOT_A + pf regs ----------
  {
    f32x4 acc[4] = {};
    gemm64(wsb + 28672, S16 + SLOT_B, w, lane, acc);
    float bia[4] = {pm2_b[c0], pm2_b[c0 + 1], pm2_b[c0 + 2], pm2_b[c0 + 3]};
    #pragma unroll
    for (int nt = 0; nt < 4; ++nt) {
      int n = nt * 16 + l15;
      f32x4 v;
      #pragma unroll
      for (int r = 0; r < 4; ++r) v[r] = acc[nt][r] + bia[r];
      pfs[nt] = v;
      *reinterpret_cast<uint2*>(S16 + FRAG_OFF(c0, n)) = pk4(v[0], v[1], v[2], v[3]);
    }
  }
  __syncthreads();

  // ---------- Phase 5: Q@SLOT_B, K@KBASE (bf16 [n][72]); V@VBASE (bf16 [c][72]) ----------
  {
    f32x4 acc[4] = {};
    gemm64(wsb + 32768, S16, w, lane, acc);   // AQ (pre-scaled)
    #pragma unroll
    for (int nt = 0; nt < 4; ++nt) {
      int n = nt * 16 + l15;
      *reinterpret_cast<uint2*>(S16 + SLOT_B + n * 72 + c0) =
          pk4(acc[nt][0] + wsf[8192 + c0], acc[nt][1] + wsf[8192 + c0 + 1],
              acc[nt][2] + wsf[8192 + c0 + 2], acc[nt][3] + wsf[8192 + c0 + 3]);
    }
  }
  {
    f32x4 acc[4] = {};
    gemm64(wsb + 36864, S16, w, lane, acc);   // AK
    #pragma unroll
    for (int nt = 0; nt < 4; ++nt) {
      int n = nt * 16 + l15;
      *reinterpret_cast<uint2*>(S16 + KBASE + n * 72 + c0) =
          pk4(acc[nt][0] + wsf[8256 + c0], acc[nt][1] + wsf[8256 + c0 + 1],
              acc[nt][2] + wsf[8256 + c0 + 2], acc[nt][3] + wsf[8256 + c0 + 3]);
    }
  }
  {
    f32x4 acc[4] = {};
    gemm64(wsb + 40960, S16, w, lane, acc);   // AV -> [c][72] scatter
    #pragma unroll
    for (int nt = 0; nt < 4; ++nt) {
      int n = nt * 16 + l15;
      #pragma unroll
      for (int r = 0; r < 4; ++r)
        S16[VBASE + (c0 + r) * 72 + n] = f2bf(acc[nt][r] + wsf[8320 + c0 + r]);
    }
  }
  __syncthreads();

  // ---------- Phase 6: MFMA attention; V preloaded, Pscr overlays V ----------
  {
    // 6a: preload V B-frags for both heads (rows h*8 + d)
    uint4 vb[2][2];
    #pragma unroll
    for (int rr = 0; rr < 2; ++rr) {
      int h = w + rr * 4;
      #pragma unroll
      for (int ks = 0; ks < 2; ++ks)
        vb[rr][ks] = *reinterpret_cast<const uint4*>(
            S16 + VBASE + (h * 8 + (l15 & 7)) * 72 + ks * 32 + lq * 8);
    }
    __syncthreads();   // all V reads done before Pscr overwrites the region

    const int Pb = VBASE + w * 1152;   // per-wave P scratch (2304B)
    const bool lq0 = (lq == 0);
    #pragma unroll
    for (int rr = 0; rr < 2; ++rr) {
      const int h = w + rr * 4;
      uint4 ka[4];
      #pragma unroll
      for (int mt = 0; mt < 4; ++mt) {
        uint4 t = *reinterpret_cast<const uint4*>(S16 + KBASE + (mt * 16 + l15) * 72 + h * 8);
        ka[mt].x = lq0 ? t.x : 0u; ka[mt].y = lq0 ? t.y : 0u;
        ka[mt].z = lq0 ? t.z : 0u; ka[mt].w = lq0 ? t.w : 0u;
      }
      #pragma unroll
      for (int q = 0; q < 4; ++q) {     // 16-query quarters
        uint4 qb = *reinterpret_cast<const uint4*>(S16 + SLOT_B + (q * 16 + l15) * 72 + h * 8);
        qb.x = lq0 ? qb.x : 0u; qb.y = lq0 ? qb.y : 0u;
        qb.z = lq0 ? qb.z : 0u; qb.w = lq0 ? qb.w : 0u;
        f32x4 sc[4];
        #pragma unroll
        for (int mt = 0; mt < 4; ++mt) {
          f32x4 z = {0.f, 0.f, 0.f, 0.f};
          sc[mt] = mfma16(ka[mt], qb, z);   // S[m][n=l15] in exp2 domain
        }
        // softmax denominator (no max pass; scores are small)
        float sum = 0.f;
        #pragma unroll
        for (int mt = 0; mt < 4; ++mt)
          #pragma unroll
          for (int r = 0; r < 4; ++r) {
            float e = EXP2F(sc[mt][r]);
            sc[mt][r] = e; sum += e;
          }
        sum += swz_xor16(sum);
        sum += __shfl_xor(sum, 32);
        float inv = __builtin_amdgcn_rcpf(sum);
        // normalized P -> bf16 (truncation via v_perm) -> per-wave scratch [n=l15][m]
        #pragma unroll
        for (int mt = 0; mt < 4; ++mt) {
          unsigned d0 = __builtin_amdgcn_perm(__float_as_uint(sc[mt][1] * inv),
                                              __float_as_uint(sc[mt][0] * inv), 0x07060302u);
          unsigned d1 = __builtin_amdgcn_perm(__float_as_uint(sc[mt][3] * inv),
                                              __float_as_uint(sc[mt][2] * inv), 0x07060302u);
          *reinterpret_cast<uint2*>(S16 + Pb + l15 * 72 + mt * 16 + lq * 4) = make_uint2(d0, d1);
        }
        // PV: ctx[n][d] = sum_m P[n][m] V[h*8+d][m]
        f32x4 ctx = {0.f, 0.f, 0.f, 0.f};
        #pragma unroll
        for (int ks = 0; ks < 2; ++ks) {
          uint4 pa = *reinterpret_cast<const uint4*>(S16 + Pb + l15 * 72 + ks * 32 + lq * 8);
          ctx = mfma16(pa, vb[rr][ks], ctx);
        }
        // scatter ctx (C-layout: n=q*16+lq*4+r, d=l15<8) into CTXF @SLOT_A
        if (l15 < 8) {
          const int kk = h * 8 + l15;
          #pragma unroll
          for (int r = 0; r < 4; ++r)
            S16[FRAG_OFF(kk, q * 16 + lq * 4 + r)] = f2bf(ctx[r]);
        }
      }
    }
  }
  __syncthreads();

  // ---------- Phase 7: MO @ CTXF + mo_b + geoT + pf(regs) -> H32 (f32 stride 65) ----------
  {
    f32x4 acc[4] = {};
    gemm64(wsb + 45056, S16, w, lane, acc);
    #pragma unroll
    for (int nt = 0; nt < 4; ++nt) {
      int n = nt * 16 + l15;
      #pragma unroll
      for (int r = 0; r < 4; ++r) {
        int c = c0 + r;
        S32[H32F + c * 65 + n] = acc[nt][r] + mo_b[c] + wsf[4096 + c * 64 + n] + pfs[nt][r];
      }
    }
  }
  __syncthreads();

  // ---------- Phase 8: LayerNorm over channels (per column n) -> HNF @SLOT_A ----------
  {
    int n = tid & 63, qq = tid >> 6;
    float sum = 0.f, ssq = 0.f;
    #pragma unroll
    for (int j = 0; j < 16; ++j) {
      float v = S32[H32F + (qq * 16 + j) * 65 + n];
      sum += v; ssq += v * v;
    }
    S32[LNS + tid] = sum;
    S32[LNS + 256 + tid] = ssq;
    __syncthreads();
    if (tid < 64) {
      float s = S32[LNS + tid] + S32[LNS + 64 + tid] + S32[LNS + 128 + tid] + S32[LNS + 192 + tid];
      float ss = S32[LNS + 256 + tid] + S32[LNS + 320 + tid] + S32[LNS + 384 + tid] + S32[LNS + 448 + tid];
      float mu = s * (1.0f / 64.0f);
      float var = ss * (1.0f / 64.0f) - mu * mu;
      S32[LNS + 512 + tid] = mu;
      S32[LNS + 576 + tid] = rsqrtf(var + 1e-5f);
    }
    __syncthreads();
    float mu = S32[LNS + 512 + n], rs = S32[LNS + 576 + n];
    #pragma unroll
    for (int half = 0; half < 2; ++half) {
      int ch0 = qq * 16 + half * 8;
      float vv[8];
      #pragma unroll
      for (int jj = 0; jj < 8; ++jj) {
        int c = ch0 + jj;
        vv[jj] = (S32[H32F + c * 65 + n] - mu) * rs * ln_g[c] + ln_beta[c];
      }
      uint4 u;
      u.x = cvt_pk_bf16(vv[0], vv[1]);
      u.y = cvt_pk_bf16(vv[2], vv[3]);
      u.z = cvt_pk_bf16(vv[4], vv[5]);
      u.w = cvt_pk_bf16(vv[6], vv[7]);
      *reinterpret_cast<uint4*>(S16 + FRAG_OFF(ch0, n)) = u;
    }
  }
  __syncthreads();

  // ---------- Phase 9: OUT @ HNF + out_b -> global [b][c][n] ----------
  {
    f32x4 acc[4] = {};
    gemm64(wsb + 49152, S16, w, lane, acc);
    float* ob = out + b * 4096;
    float bia[4] = {out_b[c0], out_b[c0 + 1], out_b[c0 + 2], out_b[c0 + 3]};
    #pragma unroll
    for (int nt = 0; nt < 4; ++nt) {
      int n = nt * 16 + l15;
      #pragma unroll
      for (int r = 0; r < 4; ++r)
        ob[(c0 + r) * 64 + n] = acc[nt][r] + bia[r];
    }
  }
}

extern "C" void kernel_launch(void* const* d_in, const int* in_sizes, int n_in,
                              void* d_out, int out_size, void* d_ws, size_t ws_size,
                              hipStream_t stream) {
  const float* x        = (const float*)d_in[0];
  const float* points   = (const float*)d_in[1];
  const float* conv1_w  = (const float*)d_in[2];
  const float* conv1_b  = (const float*)d_in[3];
  const float* conv2_w  = (const float*)d_in[4];
  const float* conv2_b  = (const float*)d_in[5];
  const float* pattern  = (const float*)d_in[6];
  const float* pm1_w    = (const float*)d_in[7];
  const float* pm1_b    = (const float*)d_in[8];
  const float* pm2_w    = (const float*)d_in[9];
  const float* pm2_b    = (const float*)d_in[10];
  const float* q_w      = (const float*)d_in[11];
  const float* q_b      = (const float*)d_in[12];
  const float* k_w      = (const float*)d_in[13];
  const float* k_b      = (const float*)d_in[14];
  const float* v_w      = (const float*)d_in[15];
  const float* v_b      = (const float*)d_in[16];
  const float* in_w     = (const float*)d_in[17];
  const float* in_b     = (const float*)d_in[18];
  const float* mo_w     = (const float*)d_in[19];
  const float* mo_b     = (const float*)d_in[20];
  const float* out_w    = (const float*)d_in[21];
  const float* out_b    = (const float*)d_in[22];
  const float* ln_g     = (const float*)d_in[23];
  const float* ln_beta  = (const float*)d_in[24];
  const int*   adjacency= (const int*)d_in[25];

  unsigned short* wsb = (unsigned short*)d_ws;
  float* wsf = (float*)((char*)d_ws + 106496);

  precompute_kernel<<<241, 256, 0, stream>>>(
      conv1_w, conv2_w, pm1_w, pm1_b, pm2_w, q_w, q_b, k_w, k_b, v_w, v_b,
      in_w, in_b, mo_w, out_w, pattern, points, adjacency, wsb, wsf);

  fused_kernel<<<2048, 256, 0, stream>>>(
      x, wsb, wsf, conv1_b, conv2_b, pm2_b, mo_b, out_b, ln_g, ln_beta,
      (float*)d_out);
}